// Round 1
// baseline (361.044 us; speedup 1.0000x reference)
//
#include <hip/hip_runtime.h>
#include <math.h>

// DeltaCorrection: B=4,H=16,N=4096,d=64,C=64 -> BH=64 streams, 64 chunks each.
// K1: per-chunk kv (d x d) + chunk decay    (parallel, 4096 blocks)
// K2: elementwise in-place scan over chunks  (parallel over bh*i*j, 256 blocks)
// K3: scores+intra+inter fused -> output     (parallel, 4096 blocks)

#define CHUNK 64
#define DIM   64
#define LS    68   // padded LDS row stride (floats) for K1
#define NCH   64   // chunks per stream
#define NBH   64   // B*H

__device__ __forceinline__ float sigf(float x) { return 1.0f / (1.0f + expf(-x)); }

__device__ __forceinline__ void dot4(float& a, const float4 p, const float4 q) {
  a = fmaf(p.x, q.x, a);
  a = fmaf(p.y, q.y, a);
  a = fmaf(p.z, q.z, a);
  a = fmaf(p.w, q.w, a);
}

#define GETC(v, u) ((u) == 0 ? (v).x : ((u) == 1 ? (v).y : ((u) == 2 ? (v).z : (v).w)))

// quad-granular XOR-swizzled LDS index for stride-64 fp32 buffers (K3).
// keeps b128 row reads across lane-varying rows <=2-way bank conflicted.
__device__ __forceinline__ int lidx(int row, int col) {
  return (row << 6) + ((((col >> 2) ^ (row & 15)) << 2) | (col & 3));
}

// ---------------------------------------------------------------------------
// K1: kv[bh][c][i][j] = sum_t beta_t * v[t][i] * khat[t][j];  decay[bh][c]
// ---------------------------------------------------------------------------
__global__ __launch_bounds__(256) void k1_kvdecay(
    const float* __restrict__ kg, const float* __restrict__ vg,
    const float* __restrict__ w_decay, const float* __restrict__ b_decay,
    const float* __restrict__ w_write, const float* __restrict__ b_write,
    float* __restrict__ ws_kv, float* __restrict__ ws_decay) {
  __shared__ float kts[DIM * LS];    // k transposed: [d][t]; beta/norm folded in
  __shared__ float vs[CHUNK * LS];   // v row-major:  [t][d]
  __shared__ float wd_s[DIM], ww_s[DIM];

  const int tid = threadIdx.x;
  const int bh  = blockIdx.x >> 6;
  const int cid = blockIdx.x & 63;
  const float* kbase = kg + (size_t)(bh * 4096 + cid * 64) * 64;
  const float* vbase = vg + (size_t)(bh * 4096 + cid * 64) * 64;

  if (tid < DIM) { wd_s[tid] = w_decay[tid]; ww_s[tid] = w_write[tid]; }

#pragma unroll
  for (int r = 0; r < 4; ++r) {
    int f = tid + 256 * r;       // 0..1023
    int t = f >> 4, d4 = f & 15;
    float4 kq = *(const float4*)(kbase + t * 64 + d4 * 4);
    kts[(d4 * 4 + 0) * LS + t] = kq.x;
    kts[(d4 * 4 + 1) * LS + t] = kq.y;
    kts[(d4 * 4 + 2) * LS + t] = kq.z;
    kts[(d4 * 4 + 3) * LS + t] = kq.w;
    float4 vq = *(const float4*)(vbase + t * 64 + d4 * 4);
    *(float4*)&vs[t * LS + d4 * 4] = vq;
  }
  __syncthreads();

  float alpha_v = 0.f;
  if (tid < CHUNK) {
    const int t = tid;
    float n2 = 0.f, dw = 0.f, da = 0.f;
#pragma unroll 8
    for (int d = 0; d < DIM; ++d) {
      float kd = kts[d * LS + t];
      n2 = fmaf(kd, kd, n2);
      dw = fmaf(kd, ww_s[d], dw);
      da = fmaf(kd, wd_s[d], da);
    }
    float beta = sigf(dw + b_write[0]);
    alpha_v    = sigf(da + b_decay[0]);
    float fold = beta / fmaxf(sqrtf(n2), 1e-12f);
#pragma unroll 8
    for (int d = 0; d < DIM; ++d) kts[d * LS + t] *= fold;  // own column only
  }
  // wave-0 reduce of alpha -> chunk decay = mean^64 (6 squarings, exact 2^6)
  if (tid < 64) {
    float s = alpha_v;
    for (int off = 32; off; off >>= 1) s += __shfl_down(s, off, 64);
    if (tid == 0) {
      float m = s * (1.0f / 64.0f);
      float p = m * m; p = p * p; p = p * p; p = p * p; p = p * p; p = p * p;
      ws_decay[bh * NCH + cid] = p;
    }
  }
  __syncthreads();

  // kv(i,j) = sum_t vs[t][i] * kts[j][t]; thread tile: i blocked (4a..4a+3),
  // j cyclic (b, b+16, b+32, b+48) to keep b128 reads <=2-way conflicted.
  const int a = tid >> 4;
  const int b = tid & 15;
  float acc[4][4];
#pragma unroll
  for (int x = 0; x < 4; ++x)
#pragma unroll
    for (int y = 0; y < 4; ++y) acc[x][y] = 0.f;

  for (int t = 0; t < CHUNK; t += 4) {
    float4 vv[4], kk[4];
#pragma unroll
    for (int tt = 0; tt < 4; ++tt) vv[tt] = *(const float4*)&vs[(t + tt) * LS + a * 4];
#pragma unroll
    for (int jj = 0; jj < 4; ++jj) kk[jj] = *(const float4*)&kts[(b + 16 * jj) * LS + t];
#pragma unroll
    for (int tt = 0; tt < 4; ++tt) {
      float4 vvt = vv[tt];
#pragma unroll
      for (int jj = 0; jj < 4; ++jj) {
        float kc = GETC(kk[jj], tt);
        acc[0][jj] = fmaf(vvt.x, kc, acc[0][jj]);
        acc[1][jj] = fmaf(vvt.y, kc, acc[1][jj]);
        acc[2][jj] = fmaf(vvt.z, kc, acc[2][jj]);
        acc[3][jj] = fmaf(vvt.w, kc, acc[3][jj]);
      }
    }
  }
  float* kvout = ws_kv + (size_t)(bh * NCH + cid) * 4096;
#pragma unroll
  for (int ii = 0; ii < 4; ++ii)
#pragma unroll
    for (int jj = 0; jj < 4; ++jj)
      kvout[(a * 4 + ii) * 64 + (b + 16 * jj)] = acc[ii][jj];
}

// ---------------------------------------------------------------------------
// K2: in-place scan. After: slot c holds S_{c-1} (slot 0 = zeros).
// Elementwise in (i,j): thread owns one float4 across all 64 chunks.
// ---------------------------------------------------------------------------
__global__ __launch_bounds__(256) void k2_scan(float* __restrict__ ws_kv,
                                               const float* __restrict__ ws_decay) {
  const int blk = blockIdx.x;                    // 256 blocks
  const int bh  = blk >> 2;
  const int pos = (blk & 3) * 256 + threadIdx.x; // float4 index 0..1023
  float4* base  = (float4*)ws_kv + (size_t)bh * 65536 + pos;
  const float* dec = ws_decay + bh * NCH;
  float4 S = make_float4(0.f, 0.f, 0.f, 0.f);
#pragma unroll 4
  for (int c = 0; c < NCH; ++c) {
    float4 kv = base[(size_t)c * 1024];  // read kv_c before overwrite
    float dcy = dec[c];
    base[(size_t)c * 1024] = S;          // store S_{c-1}
    S.x = fmaf(dcy, S.x, kv.x);
    S.y = fmaf(dcy, S.y, kv.y);
    S.z = fmaf(dcy, S.z, kv.z);
    S.w = fmaf(dcy, S.w, kv.w);
  }
}

// ---------------------------------------------------------------------------
// K3: out(t,i) = [ sum_j scores(t,j)*v(j,i) + sum_j S(i,j)*q(t,j) ] * scale
//      scores(t,j) = (j<=t) * dot(q_t, beta_j*khat_j)
// LDS: 4 swizzled 16KB buffers = exactly 64KB.
// ---------------------------------------------------------------------------
__global__ __launch_bounds__(256) void k3_out(
    const float* __restrict__ qg, const float* __restrict__ kg,
    const float* __restrict__ vg,
    const float* __restrict__ w_write, const float* __restrict__ b_write,
    const float* __restrict__ out_scale,
    const float* __restrict__ ws_kv, float* __restrict__ outg) {
  __shared__ float qs[CHUNK * 64];   // [t][d]
  __shared__ float ks[CHUNK * 64];   // k folded; reused for S after scores
  __shared__ float vts[DIM * 64];    // v transposed [d][t]
  __shared__ float ss[CHUNK * 64];   // scores [t][j]

  const int tid = threadIdx.x;
  const int bh  = blockIdx.x >> 6;
  const int cid = blockIdx.x & 63;
  const size_t gbase = (size_t)(bh * 4096 + cid * 64) * 64;

#pragma unroll
  for (int r = 0; r < 4; ++r) {
    int f = tid + 256 * r;
    int t = f >> 4, d4 = f & 15;
    float4 qq = *(const float4*)(qg + gbase + t * 64 + d4 * 4);
    *(float4*)&qs[lidx(t, d4 * 4)] = qq;
    float4 kk = *(const float4*)(kg + gbase + t * 64 + d4 * 4);
    *(float4*)&ks[lidx(t, d4 * 4)] = kk;
    float4 vv = *(const float4*)(vg + gbase + t * 64 + d4 * 4);
    vts[lidx(d4 * 4 + 0, t)] = vv.x;
    vts[lidx(d4 * 4 + 1, t)] = vv.y;
    vts[lidx(d4 * 4 + 2, t)] = vv.z;
    vts[lidx(d4 * 4 + 3, t)] = vv.w;
  }
  __syncthreads();

  if (tid < CHUNK) {
    const int t = tid;
    float n2 = 0.f, dw = 0.f;
#pragma unroll 8
    for (int d = 0; d < DIM; ++d) {
      float kd = ks[lidx(t, d)];
      n2 = fmaf(kd, kd, n2);
      dw = fmaf(kd, w_write[d], dw);   // broadcast, L1-cached
    }
    float beta = sigf(dw + b_write[0]);
    float fold = beta / fmaxf(sqrtf(n2), 1e-12f);
#pragma unroll 8
    for (int d = 0; d < DIM; ++d) ks[lidx(t, d)] *= fold;  // own row only
  }
  __syncthreads();

  const int t4 = tid >> 4;  // row-cyclic: t in {t4, t4+16, t4+32, t4+48}
  const int j4 = tid & 15;  // col-cyclic: j in {j4, j4+16, j4+32, j4+48}

  {  // scores
    float acc[4][4];
#pragma unroll
    for (int x = 0; x < 4; ++x)
#pragma unroll
      for (int y = 0; y < 4; ++y) acc[x][y] = 0.f;
    for (int c = 0; c < DIM; c += 4) {
      float4 q4[4], k4[4];
#pragma unroll
      for (int tt = 0; tt < 4; ++tt) q4[tt] = *(const float4*)&qs[lidx(t4 + 16 * tt, c)];
#pragma unroll
      for (int jj = 0; jj < 4; ++jj) k4[jj] = *(const float4*)&ks[lidx(j4 + 16 * jj, c)];
#pragma unroll
      for (int tt = 0; tt < 4; ++tt)
#pragma unroll
        for (int jj = 0; jj < 4; ++jj) dot4(acc[tt][jj], q4[tt], k4[jj]);
    }
#pragma unroll
    for (int tt = 0; tt < 4; ++tt)
#pragma unroll
      for (int jj = 0; jj < 4; ++jj) {
        int t = t4 + 16 * tt, j = j4 + 16 * jj;
        ss[lidx(t, j)] = (j <= t) ? acc[tt][jj] : 0.f;  // causal mask
      }
  }
  __syncthreads();

  {  // overwrite ks with S_{c-1}
    const float* Sg = ws_kv + (size_t)(bh * NCH + cid) * 4096;
#pragma unroll
    for (int r = 0; r < 4; ++r) {
      int f = tid + 256 * r;
      int i = f >> 4, c4 = f & 15;
      float4 sv = *(const float4*)(Sg + i * 64 + c4 * 4);
      *(float4*)&ks[lidx(i, c4 * 4)] = sv;
    }
  }
  __syncthreads();

  {  // fused intra + inter
    const int i4 = j4;
    float acc[4][4];
#pragma unroll
    for (int x = 0; x < 4; ++x)
#pragma unroll
      for (int y = 0; y < 4; ++y) acc[x][y] = 0.f;
    for (int c = 0; c < CHUNK; c += 4) {
      float4 s4[4], q4[4], v4[4], S4[4];
#pragma unroll
      for (int tt = 0; tt < 4; ++tt) {
        s4[tt] = *(const float4*)&ss[lidx(t4 + 16 * tt, c)];
        q4[tt] = *(const float4*)&qs[lidx(t4 + 16 * tt, c)];
      }
#pragma unroll
      for (int ii = 0; ii < 4; ++ii) {
        v4[ii] = *(const float4*)&vts[lidx(i4 + 16 * ii, c)];
        S4[ii] = *(const float4*)&ks[lidx(i4 + 16 * ii, c)];
      }
#pragma unroll
      for (int tt = 0; tt < 4; ++tt)
#pragma unroll
        for (int ii = 0; ii < 4; ++ii) {
          dot4(acc[tt][ii], s4[tt], v4[ii]);  // intra
          dot4(acc[tt][ii], q4[tt], S4[ii]);  // inter
        }
    }
    const float osc = out_scale[0];
#pragma unroll
    for (int tt = 0; tt < 4; ++tt)
#pragma unroll
      for (int ii = 0; ii < 4; ++ii)
        outg[gbase + (t4 + 16 * tt) * 64 + (i4 + 16 * ii)] = acc[tt][ii] * osc;
  }
}

// ---------------------------------------------------------------------------
extern "C" void kernel_launch(void* const* d_in, const int* in_sizes, int n_in,
                              void* d_out, int out_size, void* d_ws, size_t ws_size,
                              hipStream_t stream) {
  const float* q         = (const float*)d_in[0];
  const float* k         = (const float*)d_in[1];
  const float* v         = (const float*)d_in[2];
  const float* w_decay   = (const float*)d_in[3];
  const float* b_decay   = (const float*)d_in[4];
  const float* w_write   = (const float*)d_in[5];
  const float* b_write   = (const float*)d_in[6];
  const float* out_scale = (const float*)d_in[7];
  float* out = (float*)d_out;

  float* ws_kv    = (float*)d_ws;                    // 64*64*4096 floats = 64MB
  float* ws_decay = ws_kv + (size_t)NBH * NCH * 4096; // 4096 floats

  k1_kvdecay<<<dim3(NBH * NCH), dim3(256), 0, stream>>>(
      k, v, w_decay, b_decay, w_write, b_write, ws_kv, ws_decay);
  k2_scan<<<dim3(256), dim3(256), 0, stream>>>(ws_kv, ws_decay);
  k3_out<<<dim3(NBH * NCH), dim3(256), 0, stream>>>(
      q, k, v, w_write, b_write, out_scale, ws_kv, out);
}

// Round 3
// 282.713 us; speedup vs baseline: 1.2771x; 1.2771x over previous
//
#include <hip/hip_runtime.h>
#include <math.h>

// DeltaCorrection via split-bf16 MFMA (3-term Ootomo: hi*hi + hi*lo + lo*hi).
// K1: per-chunk kv (d x d) + chunk decay      (4096 blocks, MFMA)
// K2: elementwise in-place scan over chunks   (256 blocks, 8-deep pipelined)
// K3: scoresT -> masked ss -> out = q*S^T + ss*v  (4096 blocks, MFMA)

#define NCH 64
#define NBH 64

typedef __attribute__((ext_vector_type(8))) short bf16x8;
typedef __attribute__((ext_vector_type(4))) float f32x4;
typedef unsigned short ushort_t;

#define MFMA(a, b, c) __builtin_amdgcn_mfma_f32_16x16x32_bf16(a, b, c, 0, 0, 0)

__device__ __forceinline__ float sigf(float x) { return 1.0f / (1.0f + expf(-x)); }

// byte offset into a [64][64] bf16 LDS array, XOR-swizzled so that b128 reads
// across lane-varying rows at fixed 16B col-slot spread over 8 bank-slots.
__device__ __forceinline__ int swb(int row, int col) {
  return ((row << 7) + (col << 1)) ^ ((row & 7) << 4);
}

// split fp32 -> truncated bf16 hi + bf16(residual) lo.  |x - hi - lo| <= 2^-16 |x|
__device__ __forceinline__ void split1(float x, ushort_t& h, ushort_t& l) {
  unsigned xb = __float_as_uint(x);
  h = (ushort_t)(xb >> 16);
  float hf = __uint_as_float(xb & 0xFFFF0000u);
  float lf = x - hf;
  l = (ushort_t)(__float_as_uint(lf) >> 16);
}

// store float4 as hi/lo bf16, b64-packed, at (row, col..col+3)
__device__ __forceinline__ void st_split4(char* bh, char* bl, int row, int col, float4 v) {
  ushort_t h0, h1, h2, h3, l0, l1, l2, l3;
  split1(v.x, h0, l0); split1(v.y, h1, l1); split1(v.z, h2, l2); split1(v.w, h3, l3);
  uint2 hp, lp;
  hp.x = (unsigned)h0 | ((unsigned)h1 << 16); hp.y = (unsigned)h2 | ((unsigned)h3 << 16);
  lp.x = (unsigned)l0 | ((unsigned)l1 << 16); lp.y = (unsigned)l2 | ((unsigned)l3 << 16);
  int o = swb(row, col);
  *(uint2*)(bh + o) = hp;
  *(uint2*)(bl + o) = lp;
}

// A/B fragment load for mfma_f32_16x16x32_bf16:
// lane holds rows mrow+(lane&15), k = kk + (lane>>4)*8 .. +7 (contiguous)
__device__ __forceinline__ bf16x8 ldfrag(const char* base, int mrow, int kk, int lane) {
  int r = mrow + (lane & 15);
  int c = kk + ((lane >> 4) << 3);
  return *(const bf16x8*)(base + swb(r, c));
}

// ---------------------------------------------------------------------------
// K1: kv[i][j] = sum_t v[t][i] * (beta_t * khat[t][j]);  decay[bh][c]
// ---------------------------------------------------------------------------
__global__ __launch_bounds__(256) void k1_kvdecay(
    const float* __restrict__ kg, const float* __restrict__ vg,
    const float* __restrict__ w_decay, const float* __restrict__ b_decay,
    const float* __restrict__ w_write, const float* __restrict__ b_write,
    float* __restrict__ ws_kv, float* __restrict__ ws_decay) {
  __shared__ uint4 smraw[3072];  // 48 KB
  __shared__ float abuf[64];
  char* sm = (char*)smraw;
  char* KT_H = sm;             // kf^T [j][t] hi   (j = feature, t = time)
  char* KT_L = sm + 8192;
  char* VT_H = sm + 16384;     // v^T  [i][t]
  char* VT_L = sm + 24576;
  float* obuf = (float*)(sm + 32768);  // [i][j] fp32, 16 KB

  const int tid = threadIdx.x;
  const int lane = tid & 63, wv = tid >> 6;
  const int bh = blockIdx.x >> 6, cid = blockIdx.x & 63;
  const size_t gbase = (size_t)(bh * 4096 + cid * 64) * 64;

  // ---- load + gates + scatter-transpose staging ----
  {
    const int t = tid >> 2, g = tid & 3;
    const float* kp = kg + gbase + t * 64 + g * 16;
    const float* vp = vg + gbase + t * 64 + g * 16;
    float4 kr[4], vr[4];
#pragma unroll
    for (int u = 0; u < 4; ++u) { kr[u] = *(const float4*)(kp + 4 * u); vr[u] = *(const float4*)(vp + 4 * u); }
    float n2 = 0.f, dw = 0.f, da = 0.f;
#pragma unroll
    for (int u = 0; u < 4; ++u) {
      const float* wwp = w_write + g * 16 + 4 * u;
      const float* wdp = w_decay + g * 16 + 4 * u;
      float4 k4 = kr[u];
      n2 = fmaf(k4.x, k4.x, fmaf(k4.y, k4.y, fmaf(k4.z, k4.z, fmaf(k4.w, k4.w, n2))));
      dw = fmaf(k4.x, wwp[0], fmaf(k4.y, wwp[1], fmaf(k4.z, wwp[2], fmaf(k4.w, wwp[3], dw))));
      da = fmaf(k4.x, wdp[0], fmaf(k4.y, wdp[1], fmaf(k4.z, wdp[2], fmaf(k4.w, wdp[3], da))));
    }
    n2 += __shfl_xor(n2, 1, 64); n2 += __shfl_xor(n2, 2, 64);
    dw += __shfl_xor(dw, 1, 64); dw += __shfl_xor(dw, 2, 64);
    da += __shfl_xor(da, 1, 64); da += __shfl_xor(da, 2, 64);
    float beta  = sigf(dw + b_write[0]);
    float alpha = sigf(da + b_decay[0]);
    float fold  = beta / fmaxf(sqrtf(n2), 1e-12f);
    if (g == 0) abuf[t] = alpha;
#pragma unroll
    for (int u = 0; u < 4; ++u) {
      float kf[4] = {kr[u].x * fold, kr[u].y * fold, kr[u].z * fold, kr[u].w * fold};
      float vf[4] = {vr[u].x, vr[u].y, vr[u].z, vr[u].w};
#pragma unroll
      for (int e = 0; e < 4; ++e) {
        int row = g * 16 + 4 * u + e;
        ushort_t h, l;
        int o = swb(row, t);
        split1(kf[e], h, l);
        *(ushort_t*)(KT_H + o) = h; *(ushort_t*)(KT_L + o) = l;
        split1(vf[e], h, l);
        *(ushort_t*)(VT_H + o) = h; *(ushort_t*)(VT_L + o) = l;
      }
    }
  }
  __syncthreads();

  // ---- chunk decay (wave 0) ----
  if (tid < 64) {
    float a = abuf[tid];
    for (int off = 32; off; off >>= 1) a += __shfl_down(a, off, 64);
    if (tid == 0) {
      float m = a * (1.0f / 64.0f);
      float p = m * m; p = p * p; p = p * p; p = p * p; p = p * p; p = p * p;  // m^64
      ws_decay[bh * NCH + cid] = p;
    }
  }

  // ---- kv = mfma(A=v^T [i][t], B-src=kf^T [j][t]) -> D[i][j] ----
  f32x4 z = {0.f, 0.f, 0.f, 0.f};
  f32x4 acc[4] = {z, z, z, z};
#pragma unroll
  for (int kk = 0; kk < 64; kk += 32) {
    bf16x8 ah = ldfrag(VT_H, wv * 16, kk, lane);
    bf16x8 al = ldfrag(VT_L, wv * 16, kk, lane);
#pragma unroll
    for (int jb = 0; jb < 4; ++jb) {
      bf16x8 bh_ = ldfrag(KT_H, jb * 16, kk, lane);
      bf16x8 bl_ = ldfrag(KT_L, jb * 16, kk, lane);
      acc[jb] = MFMA(ah, bh_, acc[jb]);
      acc[jb] = MFMA(ah, bl_, acc[jb]);
      acc[jb] = MFMA(al, bh_, acc[jb]);
    }
  }
#pragma unroll
  for (int jb = 0; jb < 4; ++jb) {
    int j = jb * 16 + (lane & 15);
    int i0 = wv * 16 + ((lane >> 4) << 2);
#pragma unroll
    for (int r = 0; r < 4; ++r) obuf[(i0 + r) * 64 + j] = acc[jb][r];
  }
  __syncthreads();
  float* kvout = ws_kv + (size_t)(bh * NCH + cid) * 4096;
#pragma unroll
  for (int rr = 0; rr < 4; ++rr) {
    int f = tid + 256 * rr;
    *(float4*)(kvout + f * 4) = *(const float4*)(obuf + f * 4);
  }
}

// ---------------------------------------------------------------------------
// K2: in-place scan; after: slot c holds S_{c-1} (slot 0 = zeros).
// 8-deep statically-indexed load pipeline for latency hiding at 1 wave/SIMD.
// ---------------------------------------------------------------------------
__global__ __launch_bounds__(256) void k2_scan(float* __restrict__ ws_kv,
                                               const float* __restrict__ ws_decay) {
  const int bh = blockIdx.x >> 2;
  const int pos = (blockIdx.x & 3) * 256 + threadIdx.x;
  float4* base = (float4*)ws_kv + (size_t)bh * 65536 + pos;
  const float* dec = ws_decay + bh * NCH;
  float4 S = make_float4(0.f, 0.f, 0.f, 0.f);
#pragma unroll
  for (int gq = 0; gq < 8; ++gq) {
    float4 buf[8];
#pragma unroll
    for (int j = 0; j < 8; ++j) buf[j] = base[(size_t)(gq * 8 + j) * 1024];
#pragma unroll
    for (int j = 0; j < 8; ++j) {
      int c = gq * 8 + j;
      float dcy = dec[c];
      base[(size_t)c * 1024] = S;
      S.x = fmaf(dcy, S.x, buf[j].x);
      S.y = fmaf(dcy, S.y, buf[j].y);
      S.z = fmaf(dcy, S.z, buf[j].z);
      S.w = fmaf(dcy, S.w, buf[j].w);
    }
  }
}

// ---------------------------------------------------------------------------
// K3: ssT[j][t] = kf[j].q[t] (masked j<=t) ; out[t][i] = q.S^T + ss.v , *scale
// LDS 64KB: QS,KS,VT,SS (hi/lo each 8KB). PS aliases KS; obuf aliases QS.
// ---------------------------------------------------------------------------
__global__ __launch_bounds__(256) void k3_out(
    const float* __restrict__ qg, const float* __restrict__ kg,
    const float* __restrict__ vg,
    const float* __restrict__ w_write, const float* __restrict__ b_write,
    const float* __restrict__ out_scale,
    const float* __restrict__ ws_kv, float* __restrict__ outg) {
  __shared__ uint4 smraw[4096];  // 64 KB
  char* sm = (char*)smraw;
  char* QS_H = sm;             char* QS_L = sm + 8192;   // q   [t][d]
  char* KS_H = sm + 16384;     char* KS_L = sm + 24576;  // kf  [j][d]
  char* VT_H = sm + 32768;     char* VT_L = sm + 40960;  // v^T [i][t]
  char* SS_H = sm + 49152;     char* SS_L = sm + 57344;  // S   [i][j]
  char* PS_H = KS_H;           char* PS_L = KS_L;        // ss  [t][j] (aliases KS)
  float* obuf = (float*)sm;                              // out [t][i] fp32 (aliases QS)

  const int tid = threadIdx.x;
  const int lane = tid & 63, wv = tid >> 6;
  const int bh = blockIdx.x >> 6, cid = blockIdx.x & 63;
  const size_t gbase = (size_t)(bh * 4096 + cid * 64) * 64;
  const float* Sg = ws_kv + (size_t)(bh * NCH + cid) * 4096;

  // ---- stage q, S, v ----
#pragma unroll
  for (int rr = 0; rr < 4; ++rr) {
    int f = tid + 256 * rr;
    int row = f >> 4, c4 = (f & 15) * 4;
    float4 qq = *(const float4*)(qg + gbase + row * 64 + c4);
    st_split4(QS_H, QS_L, row, c4, qq);
    float4 sv = *(const float4*)(Sg + row * 64 + c4);
    st_split4(SS_H, SS_L, row, c4, sv);
    float4 vv = *(const float4*)(vg + gbase + row * 64 + c4);
    float vf[4] = {vv.x, vv.y, vv.z, vv.w};
#pragma unroll
    for (int e = 0; e < 4; ++e) {
      ushort_t h, l;
      split1(vf[e], h, l);
      int o = swb(c4 + e, row);
      *(ushort_t*)(VT_H + o) = h; *(ushort_t*)(VT_L + o) = l;
    }
  }
  // ---- stage kf (fold beta/norm in registers) ----
  {
    const int t = tid >> 2, g = tid & 3;
    const float* kp = kg + gbase + t * 64 + g * 16;
    float4 kr[4];
#pragma unroll
    for (int u = 0; u < 4; ++u) kr[u] = *(const float4*)(kp + 4 * u);
    float n2 = 0.f, dw = 0.f;
#pragma unroll
    for (int u = 0; u < 4; ++u) {
      const float* wwp = w_write + g * 16 + 4 * u;
      float4 k4 = kr[u];
      n2 = fmaf(k4.x, k4.x, fmaf(k4.y, k4.y, fmaf(k4.z, k4.z, fmaf(k4.w, k4.w, n2))));
      dw = fmaf(k4.x, wwp[0], fmaf(k4.y, wwp[1], fmaf(k4.z, wwp[2], fmaf(k4.w, wwp[3], dw))));
    }
    n2 += __shfl_xor(n2, 1, 64); n2 += __shfl_xor(n2, 2, 64);
    dw += __shfl_xor(dw, 1, 64); dw += __shfl_xor(dw, 2, 64);
    float beta = sigf(dw + b_write[0]);
    float fold = beta / fmaxf(sqrtf(n2), 1e-12f);
#pragma unroll
    for (int u = 0; u < 4; ++u) {
      float4 kf4 = make_float4(kr[u].x * fold, kr[u].y * fold, kr[u].z * fold, kr[u].w * fold);
      st_split4(KS_H, KS_L, t, g * 16 + 4 * u, kf4);
    }
  }
  __syncthreads();

  // ---- phase A: ssT[j][t] = sum_d kf[j][d] q[t][d] ----
  f32x4 z = {0.f, 0.f, 0.f, 0.f};
  f32x4 accs[4] = {z, z, z, z};
#pragma unroll
  for (int kk = 0; kk < 64; kk += 32) {
    bf16x8 ah = ldfrag(KS_H, wv * 16, kk, lane);
    bf16x8 al = ldfrag(KS_L, wv * 16, kk, lane);
#pragma unroll
    for (int nb = 0; nb < 4; ++nb) {
      bf16x8 bh_ = ldfrag(QS_H, nb * 16, kk, lane);
      bf16x8 bl_ = ldfrag(QS_L, nb * 16, kk, lane);
      accs[nb] = MFMA(ah, bh_, accs[nb]);
      accs[nb] = MFMA(ah, bl_, accs[nb]);
      accs[nb] = MFMA(al, bh_, accs[nb]);
    }
  }
  __syncthreads();  // all phase-A reads of KS/QS done -> PS may overwrite KS

  // write masked scores to PS [t][j] (b64-packed: 4 consecutive j per reg quad)
#pragma unroll
  for (int nb = 0; nb < 4; ++nb) {
    int tcol = nb * 16 + (lane & 15);
    int j0 = wv * 16 + ((lane >> 4) << 2);
    float x0 = (j0 + 0 <= tcol) ? accs[nb][0] : 0.f;
    float x1 = (j0 + 1 <= tcol) ? accs[nb][1] : 0.f;
    float x2 = (j0 + 2 <= tcol) ? accs[nb][2] : 0.f;
    float x3 = (j0 + 3 <= tcol) ? accs[nb][3] : 0.f;
    st_split4(PS_H, PS_L, tcol, j0, make_float4(x0, x1, x2, x3));
  }
  __syncthreads();

  // ---- phase B: out[t][i] = sum_j q[t][j] S[i][j]  +  sum_j ss[t][j] vT[i][j] ----
  f32x4 acco[4] = {z, z, z, z};
#pragma unroll
  for (int kk = 0; kk < 64; kk += 32) {
    bf16x8 ah = ldfrag(QS_H, wv * 16, kk, lane);
    bf16x8 al = ldfrag(QS_L, wv * 16, kk, lane);
#pragma unroll
    for (int ib = 0; ib < 4; ++ib) {
      bf16x8 bh_ = ldfrag(SS_H, ib * 16, kk, lane);
      bf16x8 bl_ = ldfrag(SS_L, ib * 16, kk, lane);
      acco[ib] = MFMA(ah, bh_, acco[ib]);
      acco[ib] = MFMA(ah, bl_, acco[ib]);
      acco[ib] = MFMA(al, bh_, acco[ib]);
    }
  }
#pragma unroll
  for (int kk = 0; kk < 64; kk += 32) {
    bf16x8 ah = ldfrag(PS_H, wv * 16, kk, lane);
    bf16x8 al = ldfrag(PS_L, wv * 16, kk, lane);
#pragma unroll
    for (int ib = 0; ib < 4; ++ib) {
      bf16x8 bh_ = ldfrag(VT_H, ib * 16, kk, lane);
      bf16x8 bl_ = ldfrag(VT_L, ib * 16, kk, lane);
      acco[ib] = MFMA(ah, bh_, acco[ib]);
      acco[ib] = MFMA(ah, bl_, acco[ib]);
      acco[ib] = MFMA(al, bh_, acco[ib]);
    }
  }
  __syncthreads();  // all phase-B reads done -> obuf may overwrite QS

  const float osc = out_scale[0];
#pragma unroll
  for (int ib = 0; ib < 4; ++ib) {
    int i = ib * 16 + (lane & 15);
    int t0 = wv * 16 + ((lane >> 4) << 2);
#pragma unroll
    for (int r = 0; r < 4; ++r) obuf[(t0 + r) * 64 + i] = acco[ib][r] * osc;
  }
  __syncthreads();
#pragma unroll
  for (int rr = 0; rr < 4; ++rr) {
    int f = tid + 256 * rr;
    *(float4*)(outg + gbase + f * 4) = *(const float4*)(obuf + f * 4);
  }
}

// ---------------------------------------------------------------------------
extern "C" void kernel_launch(void* const* d_in, const int* in_sizes, int n_in,
                              void* d_out, int out_size, void* d_ws, size_t ws_size,
                              hipStream_t stream) {
  const float* q         = (const float*)d_in[0];
  const float* k         = (const float*)d_in[1];
  const float* v         = (const float*)d_in[2];
  const float* w_decay   = (const float*)d_in[3];
  const float* b_decay   = (const float*)d_in[4];
  const float* w_write   = (const float*)d_in[5];
  const float* b_write   = (const float*)d_in[6];
  const float* out_scale = (const float*)d_in[7];
  float* out = (float*)d_out;

  float* ws_kv    = (float*)d_ws;                       // 64MB
  float* ws_decay = ws_kv + (size_t)NBH * NCH * 4096;   // 4096 floats

  k1_kvdecay<<<dim3(NBH * NCH), dim3(256), 0, stream>>>(
      k, v, w_decay, b_decay, w_write, b_write, ws_kv, ws_decay);
  k2_scan<<<dim3(256), dim3(256), 0, stream>>>(ws_kv, ws_decay);
  k3_out<<<dim3(NBH * NCH), dim3(256), 0, stream>>>(
      q, k, v, w_write, b_write, out_scale, ws_kv, out);
}